// Round 1
// baseline (224.680 us; speedup 1.0000x reference)
//
#include <hip/hip_runtime.h>

#define SRATE 44100.0
#define L_CHUNK 256
#define SAMPLES_PER_CH 2097152
#define CHUNKS_PER_CH (SAMPLES_PER_CH / L_CHUNK)   // 8192
#define NCH 8
#define TOTAL_CHUNKS (CHUNKS_PER_CH * NCH)         // 65536
#define K2_THREADS 256
#define CHUNKS_PER_THREAD (CHUNKS_PER_CH / K2_THREADS) // 32

#ifndef M_PI
#define M_PI 3.14159265358979323846
#endif

struct CoefD { double b0, b1, b2, a1, a2; };

// one sample through the 5-stage cascade (double, for building A)
__device__ void cascade_step_d(const CoefD* cf, double* s, double x) {
    double u = x;
    #pragma unroll
    for (int i = 0; i < 5; i++) {
        double y   = cf[i].b0 * u + s[2*i];
        double s1n = cf[i].b1 * u - cf[i].a1 * y + s[2*i+1];
        double s2n = cf[i].b2 * u - cf[i].a2 * y;
        s[2*i]   = s1n;
        s[2*i+1] = s2n;
        u = y;
    }
}

// K0: compute coefficients, build A = 10x10 state transition, and matrix powers.
// mats[0..99]   = P   = A^256          (per-chunk transition)
// mats[100+d*100 .. ] = Pd[d] = (A^8192)^(2^d), d=0..7  (Kogge-Stone step matrices)
__global__ __launch_bounds__(128) void k0_setup(const float* __restrict__ eqp,
                                                float* __restrict__ coef_f,
                                                double* __restrict__ mats) {
    __shared__ CoefD cf[5];
    __shared__ double M[100];
    int t = threadIdx.x;

    if (t == 0) {
        for (int i = 0; i < 5; i++) {
            double g  = (double)eqp[i*3 + 0];
            double fc = (double)eqp[i*3 + 1];
            double q  = (double)eqp[i*3 + 2];
            double A  = pow(10.0, g / 40.0);
            double w0 = 2.0 * M_PI * (fc / SRATE);
            double al = sin(w0) / (2.0 * q);
            double c  = cos(w0);
            double b0, b1, b2, a0, a1, a2;
            if (i == 0 || i == 4) {
                double sgn = (i == 4) ? 1.0 : -1.0;
                double sA = sqrt(A);
                b0 = A * ((A + 1.0) + sgn * (A - 1.0) * c + 2.0 * sA * al);
                b1 = -2.0 * sgn * A * ((A - 1.0) + sgn * (A + 1.0) * c);
                b2 = A * ((A + 1.0) + sgn * (A - 1.0) * c - 2.0 * sA * al);
                a0 = (A + 1.0) - sgn * (A - 1.0) * c + 2.0 * sA * al;
                a1 = 2.0 * sgn * ((A - 1.0) - sgn * (A + 1.0) * c);
                a2 = (A + 1.0) - sgn * (A - 1.0) * c - 2.0 * sA * al;
            } else {
                b0 = 1.0 + al * A; b1 = -2.0 * c; b2 = 1.0 - al * A;
                a0 = 1.0 + al / A; a1 = -2.0 * c; a2 = 1.0 - al / A;
            }
            cf[i].b0 = b0 / a0; cf[i].b1 = b1 / a0; cf[i].b2 = b2 / a0;
            cf[i].a1 = a1 / a0; cf[i].a2 = a2 / a0;
            coef_f[i*5 + 0] = (float)(b0 / a0);
            coef_f[i*5 + 1] = (float)(b1 / a0);
            coef_f[i*5 + 2] = (float)(b2 / a0);
            coef_f[i*5 + 3] = (float)(a1 / a0);
            coef_f[i*5 + 4] = (float)(a2 / a0);
        }
    }
    __syncthreads();

    // Build A: column j = step(e_j, x=0)
    if (t < 10) {
        double s[10];
        for (int k = 0; k < 10; k++) s[k] = (k == t) ? 1.0 : 0.0;
        cascade_step_d(cf, s, 0.0);
        for (int r = 0; r < 10; r++) M[r*10 + t] = s[r];
    }
    __syncthreads();

    // A^256 : 8 squarings
    for (int it = 0; it < 8; it++) {
        double val = 0.0;
        if (t < 100) {
            int r = t / 10, c = t % 10;
            for (int k = 0; k < 10; k++) val += M[r*10 + k] * M[k*10 + c];
        }
        __syncthreads();
        if (t < 100) M[t] = val;
        __syncthreads();
    }
    if (t < 100) mats[t] = M[t];   // P = A^256
    __syncthreads();

    // P32 = P^32 = A^8192 : 5 more squarings
    for (int it = 0; it < 5; it++) {
        double val = 0.0;
        if (t < 100) {
            int r = t / 10, c = t % 10;
            for (int k = 0; k < 10; k++) val += M[r*10 + k] * M[k*10 + c];
        }
        __syncthreads();
        if (t < 100) M[t] = val;
        __syncthreads();
    }
    if (t < 100) mats[100 + t] = M[t];  // Pd[0] = A^8192
    __syncthreads();

    // Pd[d] = Pd[d-1]^2
    for (int d = 1; d < 8; d++) {
        double val = 0.0;
        if (t < 100) {
            int r = t / 10, c = t % 10;
            for (int k = 0; k < 10; k++) val += M[r*10 + k] * M[k*10 + c];
        }
        __syncthreads();
        if (t < 100) M[t] = val;
        __syncthreads();
        if (t < 100) mats[100 * (1 + d) + t] = M[t];
        __syncthreads();
    }
}

// K1: per-chunk zero-state cascade -> final state c_b (10 floats)
__global__ __launch_bounds__(256) void k1_partial(const float* __restrict__ x,
                                                  const float* __restrict__ coef,
                                                  float* __restrict__ cbuf) {
    int tid = blockIdx.x * blockDim.x + threadIdx.x;   // 0..TOTAL_CHUNKS-1
    int ch = tid / CHUNKS_PER_CH;
    int ck = tid % CHUNKS_PER_CH;
    const float4* xp = (const float4*)(x + (size_t)ch * SAMPLES_PER_CH
                                         + (size_t)ck * L_CHUNK);
    float b0[5], b1[5], b2[5], a1[5], a2[5];
    #pragma unroll
    for (int i = 0; i < 5; i++) {
        b0[i] = coef[i*5+0]; b1[i] = coef[i*5+1]; b2[i] = coef[i*5+2];
        a1[i] = coef[i*5+3]; a2[i] = coef[i*5+4];
    }
    float s[10];
    #pragma unroll
    for (int k = 0; k < 10; k++) s[k] = 0.0f;

    float4 cur = xp[0];
    for (int i = 0; i < L_CHUNK/4; i++) {
        float4 nxt;
        if (i + 1 < L_CHUNK/4) nxt = xp[i+1];
        float xs[4] = {cur.x, cur.y, cur.z, cur.w};
        #pragma unroll
        for (int j = 0; j < 4; j++) {
            float u = xs[j];
            #pragma unroll
            for (int st = 0; st < 5; st++) {
                float y  = fmaf(b0[st], u, s[2*st]);
                float t1 = fmaf(b1[st], u, s[2*st+1]);
                s[2*st+1] = fmaf(-a2[st], y, b2[st] * u);
                s[2*st]   = fmaf(-a1[st], y, t1);
                u = y;
            }
        }
        cur = nxt;
    }
    float* cb = cbuf + (size_t)tid * 10;
    #pragma unroll
    for (int k = 0; k < 10; k++) cb[k] = s[k];
}

// K2: per-channel scan over chunk contributions -> initial state per chunk
__global__ __launch_bounds__(K2_THREADS) void k2_scan(const double* __restrict__ mats,
                                                      const float* __restrict__ cbuf,
                                                      float* __restrict__ ibuf) {
    __shared__ double Pm[100];
    __shared__ double Pd[8][100];
    __shared__ double buf[K2_THREADS][10];
    int t = threadIdx.x;
    int ch = blockIdx.x;

    for (int i = t; i < 100; i += K2_THREADS) Pm[i] = mats[i];
    for (int i = t; i < 800; i += K2_THREADS) Pd[i/100][i%100] = mats[100 + i];
    __syncthreads();

    const float* cB = cbuf + (size_t)ch * CHUNKS_PER_CH * 10;
    float* iB = ibuf + (size_t)ch * CHUNKS_PER_CH * 10;

    // thread-serial over CHUNKS_PER_THREAD chunks from zero state
    double S[10];
    #pragma unroll
    for (int k = 0; k < 10; k++) S[k] = 0.0;
    for (int j = 0; j < CHUNKS_PER_THREAD; j++) {
        const float* c = cB + (size_t)(t * CHUNKS_PER_THREAD + j) * 10;
        double ns[10];
        #pragma unroll
        for (int r = 0; r < 10; r++) {
            double acc = (double)c[r];
            #pragma unroll
            for (int k = 0; k < 10; k++) acc += Pm[r*10 + k] * S[k];
            ns[r] = acc;
        }
        #pragma unroll
        for (int r = 0; r < 10; r++) S[r] = ns[r];
    }
    #pragma unroll
    for (int r = 0; r < 10; r++) buf[t][r] = S[r];
    __syncthreads();

    // Kogge-Stone over thread partials (matrix per step is Pd[d])
    for (int d = 0; d < 8; d++) {
        double nv[10];
        bool act = (t >= (1 << d));
        if (act) {
            int src = t - (1 << d);
            #pragma unroll
            for (int r = 0; r < 10; r++) {
                double acc = buf[t][r];
                #pragma unroll
                for (int k = 0; k < 10; k++) acc += Pd[d][r*10 + k] * buf[src][k];
                nv[r] = acc;
            }
        }
        __syncthreads();
        if (act) {
            #pragma unroll
            for (int r = 0; r < 10; r++) buf[t][r] = nv[r];
        }
        __syncthreads();
    }

    // exclusive prefix for this thread's first chunk
    double E[10];
    if (t == 0) { for (int r = 0; r < 10; r++) E[r] = 0.0; }
    else        { for (int r = 0; r < 10; r++) E[r] = buf[t-1][r]; }

    // replay: emit initial state per chunk
    for (int j = 0; j < CHUNKS_PER_THREAD; j++) {
        int idx = t * CHUNKS_PER_THREAD + j;
        float* ip = iB + (size_t)idx * 10;
        #pragma unroll
        for (int r = 0; r < 10; r++) ip[r] = (float)E[r];
        const float* c = cB + (size_t)idx * 10;
        double ns[10];
        #pragma unroll
        for (int r = 0; r < 10; r++) {
            double acc = (double)c[r];
            #pragma unroll
            for (int k = 0; k < 10; k++) acc += Pm[r*10 + k] * E[k];
            ns[r] = acc;
        }
        #pragma unroll
        for (int r = 0; r < 10; r++) E[r] = ns[r];
    }
}

// K3: re-run each chunk from its correct initial state, writing y
__global__ __launch_bounds__(256) void k3_final(const float* __restrict__ x,
                                                const float* __restrict__ coef,
                                                const float* __restrict__ ibuf,
                                                float* __restrict__ out) {
    int tid = blockIdx.x * blockDim.x + threadIdx.x;
    int ch = tid / CHUNKS_PER_CH;
    int ck = tid % CHUNKS_PER_CH;
    size_t base = (size_t)ch * SAMPLES_PER_CH + (size_t)ck * L_CHUNK;
    const float4* xp = (const float4*)(x + base);
    float4* op = (float4*)(out + base);

    float b0[5], b1[5], b2[5], a1[5], a2[5];
    #pragma unroll
    for (int i = 0; i < 5; i++) {
        b0[i] = coef[i*5+0]; b1[i] = coef[i*5+1]; b2[i] = coef[i*5+2];
        a1[i] = coef[i*5+3]; a2[i] = coef[i*5+4];
    }
    float s[10];
    const float* ip = ibuf + (size_t)tid * 10;
    #pragma unroll
    for (int k = 0; k < 10; k++) s[k] = ip[k];

    float4 cur = xp[0];
    for (int i = 0; i < L_CHUNK/4; i++) {
        float4 nxt;
        if (i + 1 < L_CHUNK/4) nxt = xp[i+1];
        float xs[4] = {cur.x, cur.y, cur.z, cur.w};
        float ys[4];
        #pragma unroll
        for (int j = 0; j < 4; j++) {
            float u = xs[j];
            #pragma unroll
            for (int st = 0; st < 5; st++) {
                float y  = fmaf(b0[st], u, s[2*st]);
                float t1 = fmaf(b1[st], u, s[2*st+1]);
                s[2*st+1] = fmaf(-a2[st], y, b2[st] * u);
                s[2*st]   = fmaf(-a1[st], y, t1);
                u = y;
            }
            ys[j] = u;
        }
        float4 yo = make_float4(ys[0], ys[1], ys[2], ys[3]);
        op[i] = yo;
        cur = nxt;
    }
}

extern "C" void kernel_launch(void* const* d_in, const int* in_sizes, int n_in,
                              void* d_out, int out_size, void* d_ws, size_t ws_size,
                              hipStream_t stream) {
    const float* x   = (const float*)d_in[0];
    const float* eqp = (const float*)d_in[1];
    float* out = (float*)d_out;
    char* ws = (char*)d_ws;

    float*  coef_f = (float*)ws;               // 25 floats
    double* mats   = (double*)(ws + 512);      // 900 doubles = 7200 B
    float*  cbuf   = (float*)(ws + 8192);                                // 65536*10 floats
    float*  ibuf   = (float*)(ws + 8192 + (size_t)TOTAL_CHUNKS * 10 * 4);

    hipLaunchKernelGGL(k0_setup, dim3(1), dim3(128), 0, stream, eqp, coef_f, mats);
    hipLaunchKernelGGL(k1_partial, dim3(TOTAL_CHUNKS / 256), dim3(256), 0, stream,
                       x, coef_f, cbuf);
    hipLaunchKernelGGL(k2_scan, dim3(NCH), dim3(K2_THREADS), 0, stream,
                       mats, cbuf, ibuf);
    hipLaunchKernelGGL(k3_final, dim3(TOTAL_CHUNKS / 256), dim3(256), 0, stream,
                       x, coef_f, ibuf, out);
}

// Round 2
// 170.834 us; speedup vs baseline: 1.3152x; 1.3152x over previous
//
#include <hip/hip_runtime.h>

#define SRATE 44100.0
#define L_CHUNK 256
#define SAMPLES_PER_CH 2097152
#define CHUNKS_PER_CH 8192            // SAMPLES_PER_CH / L_CHUNK
#define NCH 8
#define TOTAL_CHUNKS 65536
#define NBLK 256                      // TOTAL_CHUNKS / 256 (also = grid for k1/k2a/k3)
#define BLK_PER_CH 32                 // CHUNKS_PER_CH / 256
#define NWIN 16                       // windows per chunk
#define WIN 16                        // samples per window
#define STRIDE 17                     // LDS row stride in floats (bank-conflict-free)

#ifndef M_PI
#define M_PI 3.14159265358979323846
#endif

struct CoefD { double b0, b1, b2, a1, a2; };

__device__ void cascade_step_d(const CoefD* cf, double* s, double x) {
    double u = x;
    #pragma unroll
    for (int i = 0; i < 5; i++) {
        double y   = cf[i].b0 * u + s[2*i];
        double s1n = cf[i].b1 * u - cf[i].a1 * y + s[2*i+1];
        double s2n = cf[i].b2 * u - cf[i].a2 * y;
        s[2*i]   = s1n;
        s[2*i+1] = s2n;
        u = y;
    }
}

// K0: coefficients + fp32 matrix powers.
// mats_f[0..799]    : Pd[d] = A^(256*2^d), d=0..7   (k2a KS steps, k3 binary decomp)
// mats_f[800..1299] : Qe[e] = A^(65536*2^e), e=0..4 (k2b KS steps)
__global__ __launch_bounds__(128) void k0_setup(const float* __restrict__ eqp,
                                                float* __restrict__ coef_f,
                                                float* __restrict__ mats_f) {
    __shared__ CoefD cf[5];
    __shared__ double M[100];
    int t = threadIdx.x;

    if (t == 0) {
        for (int i = 0; i < 5; i++) {
            double g  = (double)eqp[i*3 + 0];
            double fc = (double)eqp[i*3 + 1];
            double q  = (double)eqp[i*3 + 2];
            double A  = pow(10.0, g / 40.0);
            double w0 = 2.0 * M_PI * (fc / SRATE);
            double al = sin(w0) / (2.0 * q);
            double c  = cos(w0);
            double b0, b1, b2, a0, a1, a2;
            if (i == 0 || i == 4) {
                double sgn = (i == 4) ? 1.0 : -1.0;
                double sA = sqrt(A);
                b0 = A * ((A + 1.0) + sgn * (A - 1.0) * c + 2.0 * sA * al);
                b1 = -2.0 * sgn * A * ((A - 1.0) + sgn * (A + 1.0) * c);
                b2 = A * ((A + 1.0) + sgn * (A - 1.0) * c - 2.0 * sA * al);
                a0 = (A + 1.0) - sgn * (A - 1.0) * c + 2.0 * sA * al;
                a1 = 2.0 * sgn * ((A - 1.0) - sgn * (A + 1.0) * c);
                a2 = (A + 1.0) - sgn * (A - 1.0) * c - 2.0 * sA * al;
            } else {
                b0 = 1.0 + al * A; b1 = -2.0 * c; b2 = 1.0 - al * A;
                a0 = 1.0 + al / A; a1 = -2.0 * c; a2 = 1.0 - al / A;
            }
            cf[i].b0 = b0 / a0; cf[i].b1 = b1 / a0; cf[i].b2 = b2 / a0;
            cf[i].a1 = a1 / a0; cf[i].a2 = a2 / a0;
            coef_f[i*5 + 0] = (float)(b0 / a0);
            coef_f[i*5 + 1] = (float)(b1 / a0);
            coef_f[i*5 + 2] = (float)(b2 / a0);
            coef_f[i*5 + 3] = (float)(a1 / a0);
            coef_f[i*5 + 4] = (float)(a2 / a0);
        }
    }
    __syncthreads();

    // A: column j = step(e_j, x=0)
    if (t < 10) {
        double s[10];
        for (int k = 0; k < 10; k++) s[k] = (k == t) ? 1.0 : 0.0;
        cascade_step_d(cf, s, 0.0);
        for (int r = 0; r < 10; r++) M[r*10 + t] = s[r];
    }
    __syncthreads();

    // repeated squaring: after k squarings, M = A^(2^k)
    for (int k = 1; k <= 20; k++) {
        double val = 0.0;
        if (t < 100) {
            int r = t / 10, c = t % 10;
            for (int j = 0; j < 10; j++) val += M[r*10 + j] * M[j*10 + c];
        }
        __syncthreads();
        if (t < 100) {
            M[t] = val;
            if (k >= 8 && k <= 15)  mats_f[(k-8)*100 + t]        = (float)val;
            if (k >= 16)            mats_f[800 + (k-16)*100 + t] = (float)val;
        }
        __syncthreads();
    }
}

// K1: per-chunk zero-state cascade via LDS-transposed coalesced tiles.
// cbuf layout: [block][r][thread]  (field-major, coalesced)
__global__ __launch_bounds__(256) void k1_partial(const float* __restrict__ x,
                                                  const float* __restrict__ coef,
                                                  float* __restrict__ cbuf) {
    __shared__ float inb[2][256 * STRIDE];
    int t = threadIdx.x, b = blockIdx.x;

    float cb0[5], cb1[5], cb2[5], ca1[5], ca2[5];
    #pragma unroll
    for (int i = 0; i < 5; i++) {
        cb0[i] = coef[i*5+0]; cb1[i] = coef[i*5+1]; cb2[i] = coef[i*5+2];
        ca1[i] = coef[i*5+3]; ca2[i] = coef[i*5+4];
    }
    const float4* x4 = (const float4*)x;
    const size_t base4 = (size_t)b * 16384;       // block region / 4
    const int cb = t >> 2, q = t & 3;             // 4 lanes per 64B line

    // prefetch window 0
    float4 rr[4];
    #pragma unroll
    for (int k = 0; k < 4; k++)
        rr[k] = x4[base4 + (size_t)(cb + 64*k) * 64 + q];
    #pragma unroll
    for (int k = 0; k < 4; k++) {
        int o = (cb + 64*k) * STRIDE + q*4;
        inb[0][o+0] = rr[k].x; inb[0][o+1] = rr[k].y;
        inb[0][o+2] = rr[k].z; inb[0][o+3] = rr[k].w;
    }
    __syncthreads();

    float s[10];
    #pragma unroll
    for (int k = 0; k < 10; k++) s[k] = 0.0f;

    for (int w = 0; w < NWIN; w++) {
        if (w + 1 < NWIN) {
            #pragma unroll
            for (int k = 0; k < 4; k++)
                rr[k] = x4[base4 + (size_t)(cb + 64*k) * 64 + (w+1)*4 + q];
        }
        const float* cur = inb[w & 1] + t * STRIDE;
        #pragma unroll
        for (int i = 0; i < WIN; i++) {
            float u = cur[i];
            #pragma unroll
            for (int st = 0; st < 5; st++) {
                float y  = fmaf(cb0[st], u, s[2*st]);
                float t1 = fmaf(cb1[st], u, s[2*st+1]);
                s[2*st+1] = fmaf(-ca2[st], y, cb2[st] * u);
                s[2*st]   = fmaf(-ca1[st], y, t1);
                u = y;
            }
        }
        __syncthreads();
        if (w + 1 < NWIN) {
            float* nb = inb[(w+1) & 1];
            #pragma unroll
            for (int k = 0; k < 4; k++) {
                int o = (cb + 64*k) * STRIDE + q*4;
                nb[o+0] = rr[k].x; nb[o+1] = rr[k].y;
                nb[o+2] = rr[k].z; nb[o+3] = rr[k].w;
            }
        }
        __syncthreads();
    }
    #pragma unroll
    for (int r = 0; r < 10; r++)
        cbuf[(size_t)b * 2560 + r * 256 + t] = s[r];
}

// K2a: per-block (256 chunks) Kogge-Stone scan. Writes local exclusive
// prefixes to ibuf ([block][r][thread]) and block aggregate to abuf.
__global__ __launch_bounds__(256) void k2a_scan(const float* __restrict__ mats_f,
                                                const float* __restrict__ cbuf,
                                                float* __restrict__ ibuf,
                                                float* __restrict__ abuf) {
    __shared__ float Mds[800];
    __shared__ float buf[256][11];
    int t = threadIdx.x, b = blockIdx.x;

    for (int i = t; i < 800; i += 256) Mds[i] = mats_f[i];

    float v[10];
    #pragma unroll
    for (int r = 0; r < 10; r++) {
        v[r] = cbuf[(size_t)b * 2560 + r * 256 + t];
        buf[t][r] = v[r];
    }
    __syncthreads();

    for (int d = 0; d < 8; d++) {
        float nv[10];
        bool act = (t >= (1 << d));
        if (act) {
            int src = t - (1 << d);
            #pragma unroll
            for (int r = 0; r < 10; r++) {
                float acc = v[r];
                #pragma unroll
                for (int k = 0; k < 10; k++)
                    acc = fmaf(Mds[d*100 + r*10 + k], buf[src][k], acc);
                nv[r] = acc;
            }
        }
        __syncthreads();
        if (act) {
            #pragma unroll
            for (int r = 0; r < 10; r++) { v[r] = nv[r]; buf[t][r] = nv[r]; }
        }
        __syncthreads();
    }

    #pragma unroll
    for (int r = 0; r < 10; r++)
        ibuf[(size_t)b * 2560 + r * 256 + t] = (t > 0) ? buf[t-1][r] : 0.0f;
    if (t == 255) {
        #pragma unroll
        for (int r = 0; r < 10; r++) abuf[b * 10 + r] = v[r];
    }
}

// K2b: scan the 32 block-aggregates per channel -> exclusive block prefixes.
__global__ __launch_bounds__(256) void k2b_scan(const float* __restrict__ mats_f,
                                                const float* __restrict__ abuf,
                                                float* __restrict__ bbuf) {
    __shared__ float Qds[500];
    __shared__ float buf[256][11];
    int t = threadIdx.x;
    int i = t & 31;                       // block-in-channel

    for (int k = t; k < 500; k += 256) Qds[k] = mats_f[800 + k];

    float v[10];
    #pragma unroll
    for (int r = 0; r < 10; r++) { v[r] = abuf[t * 10 + r]; buf[t][r] = v[r]; }
    __syncthreads();

    for (int e = 0; e < 5; e++) {
        float nv[10];
        bool act = (i >= (1 << e));
        if (act) {
            int src = t - (1 << e);
            #pragma unroll
            for (int r = 0; r < 10; r++) {
                float acc = v[r];
                #pragma unroll
                for (int k = 0; k < 10; k++)
                    acc = fmaf(Qds[e*100 + r*10 + k], buf[src][k], acc);
                nv[r] = acc;
            }
        }
        __syncthreads();
        if (act) {
            #pragma unroll
            for (int r = 0; r < 10; r++) { v[r] = nv[r]; buf[t][r] = nv[r]; }
        }
        __syncthreads();
    }
    #pragma unroll
    for (int r = 0; r < 10; r++)
        bbuf[t * 10 + r] = (i > 0) ? buf[t-1][r] : 0.0f;
}

// K3: true init = ibuf_local + A^(256*t) * Bpre[block], then re-run chunk,
// writing y through an LDS-transposed coalesced store path.
__global__ __launch_bounds__(256) void k3_final(const float* __restrict__ x,
                                                const float* __restrict__ coef,
                                                const float* __restrict__ mats_f,
                                                const float* __restrict__ ibuf,
                                                const float* __restrict__ bbuf,
                                                float* __restrict__ out) {
    __shared__ float inb[2][256 * STRIDE];
    __shared__ float outb[256 * STRIDE];
    __shared__ float Mds[800];
    int t = threadIdx.x, b = blockIdx.x;

    const float4* x4 = (const float4*)x;
    float4* o4 = (float4*)out;
    const size_t base4 = (size_t)b * 16384;
    const int cb = t >> 2, q = t & 3;

    // prefetch window 0 first so loads fly during init math
    float4 rr[4];
    #pragma unroll
    for (int k = 0; k < 4; k++)
        rr[k] = x4[base4 + (size_t)(cb + 64*k) * 64 + q];

    for (int i = t; i < 800; i += 256) Mds[i] = mats_f[i];

    float cb0[5], cb1[5], cb2[5], ca1[5], ca2[5];
    #pragma unroll
    for (int i = 0; i < 5; i++) {
        cb0[i] = coef[i*5+0]; cb1[i] = coef[i*5+1]; cb2[i] = coef[i*5+2];
        ca1[i] = coef[i*5+3]; ca2[i] = coef[i*5+4];
    }

    float s[10];
    #pragma unroll
    for (int r = 0; r < 10; r++)
        s[r] = ibuf[(size_t)b * 2560 + r * 256 + t];

    float v[10];
    #pragma unroll
    for (int r = 0; r < 10; r++) v[r] = bbuf[b * 10 + r];

    #pragma unroll
    for (int k = 0; k < 4; k++) {
        int o = (cb + 64*k) * STRIDE + q*4;
        inb[0][o+0] = rr[k].x; inb[0][o+1] = rr[k].y;
        inb[0][o+2] = rr[k].z; inb[0][o+3] = rr[k].w;
    }
    __syncthreads();   // inb[0] ready AND Mds ready

    // binary decomposition: v = A^(256*t) * Bpre
    for (int d = 0; d < 8; d++) {
        float wv[10];
        #pragma unroll
        for (int r = 0; r < 10; r++) {
            float acc = 0.0f;
            #pragma unroll
            for (int k = 0; k < 10; k++)
                acc = fmaf(Mds[d*100 + r*10 + k], v[k], acc);
            wv[r] = acc;
        }
        bool bit = (t >> d) & 1;
        #pragma unroll
        for (int r = 0; r < 10; r++) v[r] = bit ? wv[r] : v[r];
    }
    #pragma unroll
    for (int r = 0; r < 10; r++) s[r] += v[r];

    for (int w = 0; w < NWIN; w++) {
        if (w + 1 < NWIN) {
            #pragma unroll
            for (int k = 0; k < 4; k++)
                rr[k] = x4[base4 + (size_t)(cb + 64*k) * 64 + (w+1)*4 + q];
        }
        const float* cur = inb[w & 1] + t * STRIDE;
        float* orow = outb + t * STRIDE;
        #pragma unroll
        for (int i = 0; i < WIN; i++) {
            float u = cur[i];
            #pragma unroll
            for (int st = 0; st < 5; st++) {
                float y  = fmaf(cb0[st], u, s[2*st]);
                float t1 = fmaf(cb1[st], u, s[2*st+1]);
                s[2*st+1] = fmaf(-ca2[st], y, cb2[st] * u);
                s[2*st]   = fmaf(-ca1[st], y, t1);
                u = y;
            }
            orow[i] = u;
        }
        __syncthreads();   // outb complete; inb[w&1] fully consumed

        // cooperative coalesced store of window w
        #pragma unroll
        for (int k = 0; k < 4; k++) {
            int o = (cb + 64*k) * STRIDE + q*4;
            float4 ov = make_float4(outb[o+0], outb[o+1], outb[o+2], outb[o+3]);
            o4[base4 + (size_t)(cb + 64*k) * 64 + (size_t)w*4 + q] = ov;
        }
        if (w + 1 < NWIN) {
            float* nb = inb[(w+1) & 1];
            #pragma unroll
            for (int k = 0; k < 4; k++) {
                int o = (cb + 64*k) * STRIDE + q*4;
                nb[o+0] = rr[k].x; nb[o+1] = rr[k].y;
                nb[o+2] = rr[k].z; nb[o+3] = rr[k].w;
            }
        }
        __syncthreads();   // next window may read inb / overwrite outb
    }
}

extern "C" void kernel_launch(void* const* d_in, const int* in_sizes, int n_in,
                              void* d_out, int out_size, void* d_ws, size_t ws_size,
                              hipStream_t stream) {
    const float* x   = (const float*)d_in[0];
    const float* eqp = (const float*)d_in[1];
    float* out = (float*)d_out;
    char* ws = (char*)d_ws;

    float* coef_f = (float*)ws;                         // 25 floats
    float* mats_f = (float*)(ws + 256);                 // 1300 floats
    float* cbuf   = (float*)(ws + 8192);                // 65536*10 floats = 2.62 MB
    float* ibuf   = (float*)(ws + 8192 + 2621440);      // 2.62 MB
    float* abuf   = (float*)(ws + 8192 + 2*2621440);    // 2560 floats
    float* bbuf   = (float*)(ws + 8192 + 2*2621440 + 16384); // 2560 floats

    hipLaunchKernelGGL(k0_setup, dim3(1), dim3(128), 0, stream, eqp, coef_f, mats_f);
    hipLaunchKernelGGL(k1_partial, dim3(NBLK), dim3(256), 0, stream, x, coef_f, cbuf);
    hipLaunchKernelGGL(k2a_scan, dim3(NBLK), dim3(256), 0, stream, mats_f, cbuf, ibuf, abuf);
    hipLaunchKernelGGL(k2b_scan, dim3(1), dim3(256), 0, stream, mats_f, abuf, bbuf);
    hipLaunchKernelGGL(k3_final, dim3(NBLK), dim3(256), 0, stream,
                       x, coef_f, mats_f, ibuf, bbuf, out);
}